// Round 1
// baseline (63.360 us; speedup 1.0000x reference)
//
#include <hip/hip_runtime.h>
#include <stdint.h>

#define MROWS 131072
#define NSPEC 8
#define DIN   128
#define NOUT  256
#define BM    64

typedef __attribute__((ext_vector_type(8))) short s16x8;
typedef __attribute__((ext_vector_type(4))) float f32x4;

// workspace layout
#define OFF_BF    ((size_t)0)        // 8*16*4*1024 = 524288 B : W in bf16, fragment order
#define OFF_PERM  ((size_t)524288)   // M*4 = 524288 B : row permutation (sorted by species)
#define OFF_META  ((size_t)1048576)  // ints: counts[8], bases[8], cursors[8], tileOff[9]
#define WS_NEEDED ((size_t)(1048576 + 256))

__device__ __forceinline__ uint32_t bf16_1(float f) {
  union { float f; uint32_t u; } v; v.f = f;
  return (v.u + 0x7FFFu + ((v.u >> 16) & 1u)) >> 16;  // RNE, inputs are finite
}

// Convert W [8][128][256] fp32 -> bf16 in per-wave fragment order:
// chunk c = ((s*16 + nfrag)*4 + kt); within chunk lane l holds
// B[k = kt*32 + (l>>4)*8 + j][n = nfrag*16 + (l&15)], j=0..7 (16B contiguous).
// Also zeroes counts[8] (ws is NOT re-poisoned between replays).
__global__ void k_convert_init(const float* __restrict__ B, char* __restrict__ ws) {
  int gid = blockIdx.x * 256 + threadIdx.x;   // 32768 threads
  int l  = gid & 63;
  int c  = gid >> 6;                          // 0..511
  int kt = c & 3;
  int f  = (c >> 2) & 15;
  int s  = c >> 6;
  int n  = f * 16 + (l & 15);
  int k0 = kt * 32 + (l >> 4) * 8;
  const float* src = B + (size_t)s * DIN * NOUT + n;
  uint32_t w0 = bf16_1(src[(size_t)(k0 + 0) * NOUT]) | (bf16_1(src[(size_t)(k0 + 1) * NOUT]) << 16);
  uint32_t w1 = bf16_1(src[(size_t)(k0 + 2) * NOUT]) | (bf16_1(src[(size_t)(k0 + 3) * NOUT]) << 16);
  uint32_t w2 = bf16_1(src[(size_t)(k0 + 4) * NOUT]) | (bf16_1(src[(size_t)(k0 + 5) * NOUT]) << 16);
  uint32_t w3 = bf16_1(src[(size_t)(k0 + 6) * NOUT]) | (bf16_1(src[(size_t)(k0 + 7) * NOUT]) << 16);
  *(uint4*)(ws + OFF_BF + (size_t)c * 1024 + (size_t)l * 16) = make_uint4(w0, w1, w2, w3);
  if (gid < 8) ((int*)(ws + OFF_META))[gid] = 0;   // counts = 0
}

__global__ void k_hist(const int* __restrict__ sp, char* __restrict__ ws) {
  __shared__ int bins[8];
  int* counts = (int*)(ws + OFF_META);
  int t = threadIdx.x;
  if (t < 8) bins[t] = 0;
  __syncthreads();
  atomicAdd(&bins[sp[blockIdx.x * 256 + t] & 7], 1);
  __syncthreads();
  if (t < 8) atomicAdd(&counts[t], bins[t]);
}

__global__ void k_scan(char* __restrict__ ws) {
  if (threadIdx.x == 0 && blockIdx.x == 0) {
    int* meta    = (int*)(ws + OFF_META);
    int* counts  = meta;
    int* bases   = meta + 8;
    int* curs    = meta + 16;
    int* tileOff = meta + 24;                 // 9 entries
    int base = 0, toff = 0;
    tileOff[0] = 0;
    for (int s = 0; s < 8; ++s) {
      bases[s] = base; curs[s] = base;
      base += counts[s];
      toff += (counts[s] + BM - 1) >> 6;
      tileOff[s + 1] = toff;
    }
  }
}

__global__ void k_scatter(const int* __restrict__ sp, char* __restrict__ ws) {
  __shared__ int lbin[8], gbase[8];
  int* curs = (int*)(ws + OFF_META) + 16;
  int* perm = (int*)(ws + OFF_PERM);
  int t = threadIdx.x;
  if (t < 8) lbin[t] = 0;
  __syncthreads();
  int i = blockIdx.x * 256 + t;
  int s = sp[i] & 7;
  int rank = atomicAdd(&lbin[s], 1);          // within-block rank
  __syncthreads();
  if (t < 8) gbase[t] = atomicAdd(&curs[t], lbin[t]);
  __syncthreads();
  perm[gbase[s] + rank] = i;                  // order within species irrelevant
}

// One block = 64 rows (uniform species, via perm) x 256 cols. 4 waves, each 64x64.
__global__ __launch_bounds__(256) void k_gemm(const float* __restrict__ A,
                                              const char* __restrict__ ws,
                                              float* __restrict__ out) {
  const int* meta    = (const int*)(ws + OFF_META);
  const int* counts  = meta;
  const int* bases   = meta + 8;
  const int* tileOff = meta + 24;
  const int* perm    = (const int*)(ws + OFF_PERM);
  const char* Bf     = ws + OFF_BF;

  __shared__ char As[BM * 256];   // [64 rows][128 k] bf16, XOR-swizzled
  __shared__ int prow[BM];

  int b = blockIdx.x;
  if (b >= tileOff[8]) return;
  int s = 0;
  while (b >= tileOff[s + 1]) ++s;
  int i = b - tileOff[s];
  int rowStart = bases[s] + i * BM;
  int nrows = counts[s] - i * BM;
  if (nrows > BM) nrows = BM;

  int t = threadIdx.x;
  if (t < BM) prow[t] = (t < nrows) ? perm[rowStart + t] : -1;
  __syncthreads();

  // stage A: 8 rows per iteration, 32 threads per row (float4 each), fp32->bf16
  int f4 = t & 31, r0 = t >> 5;
  #pragma unroll
  for (int it = 0; it < 8; ++it) {
    int r = r0 + it * 8;
    int rid = prow[r];
    float4 v = make_float4(0.f, 0.f, 0.f, 0.f);
    if (rid >= 0) v = *(const float4*)(A + (size_t)rid * DIN + f4 * 4);
    uint32_t lo = bf16_1(v.x) | (bf16_1(v.y) << 16);
    uint32_t hi = bf16_1(v.z) | (bf16_1(v.w) << 16);
    int off = (r * 256 + f4 * 8) ^ ((r & 7) << 4);   // G4 swizzle
    *(uint2*)(As + off) = make_uint2(lo, hi);
  }
  __syncthreads();

  int w = t >> 6, l = t & 63;
  f32x4 acc[4][4];
  #pragma unroll
  for (int mi = 0; mi < 4; ++mi)
    #pragma unroll
    for (int ni = 0; ni < 4; ++ni)
      acc[mi][ni] = (f32x4){0.f, 0.f, 0.f, 0.f};

  #pragma unroll
  for (int kt = 0; kt < 4; ++kt) {
    s16x8 afr[4];
    #pragma unroll
    for (int mi = 0; mi < 4; ++mi) {
      int r = mi * 16 + (l & 15);
      int off = (r * 256 + kt * 64 + (l >> 4) * 16) ^ ((r & 7) << 4);
      afr[mi] = *(const s16x8*)(As + off);
    }
    #pragma unroll
    for (int ni = 0; ni < 4; ++ni) {
      int c = (s * 16 + (w * 4 + ni)) * 4 + kt;
      s16x8 bfr = *(const s16x8*)(Bf + (size_t)c * 1024 + (size_t)l * 16);
      #pragma unroll
      for (int mi = 0; mi < 4; ++mi)
        acc[mi][ni] = __builtin_amdgcn_mfma_f32_16x16x32_bf16(afr[mi], bfr, acc[mi][ni], 0, 0, 0);
    }
  }

  // D: row = (l>>4)*4 + q (+ mi*16), col = l&15 (+ ni*16 + w*64)
  int colBase = w * 64 + (l & 15);
  #pragma unroll
  for (int mi = 0; mi < 4; ++mi) {
    #pragma unroll
    for (int q = 0; q < 4; ++q) {
      int r = mi * 16 + ((l >> 4) << 2) + q;
      int rid = prow[r];
      if (rid >= 0) {
        #pragma unroll
        for (int ni = 0; ni < 4; ++ni)
          out[(size_t)rid * NOUT + colBase + ni * 16] = acc[mi][ni][q];
      }
    }
  }
}

// ws-free correctness fallback (only if ws_size is unexpectedly small)
__global__ void k_naive(const float* __restrict__ A, const int* __restrict__ sp,
                        const float* __restrict__ B, float* __restrict__ out) {
  __shared__ float av[DIN];
  int m = blockIdx.x;
  int n = threadIdx.x;
  if (n < DIN) av[n] = A[(size_t)m * DIN + n];
  __syncthreads();
  int s = sp[m] & 7;
  const float* b = B + (size_t)s * DIN * NOUT + n;
  float acc = 0.f;
  #pragma unroll 8
  for (int k = 0; k < DIN; ++k) acc = fmaf(av[k], b[(size_t)k * NOUT], acc);
  out[(size_t)m * NOUT + n] = acc;
}

extern "C" void kernel_launch(void* const* d_in, const int* in_sizes, int n_in,
                              void* d_out, int out_size, void* d_ws, size_t ws_size,
                              hipStream_t stream) {
  const float* values = (const float*)d_in[0];
  const int*   sp     = (const int*)d_in[1];
  const float* B      = (const float*)d_in[2];
  float*       out    = (float*)d_out;

  if (d_ws == nullptr || ws_size < WS_NEEDED) {
    k_naive<<<MROWS, NOUT, 0, stream>>>(values, sp, B, out);
    return;
  }
  char* ws = (char*)d_ws;
  k_convert_init<<<128, 256, 0, stream>>>(B, ws);
  k_hist<<<MROWS / 256, 256, 0, stream>>>(sp, ws);
  k_scan<<<1, 64, 0, stream>>>(ws);
  k_scatter<<<MROWS / 256, 256, 0, stream>>>(sp, ws);
  k_gemm<<<MROWS / BM + NSPEC, 256, 0, stream>>>(values, ws, out);
}